// Round 1
// baseline (711.430 us; speedup 1.0000x reference)
//
#include <hip/hip_runtime.h>
#include <math.h>

#define B_ 128
#define S_ 256
#define H_ 1024
#define E_ 512
#define V_ 32000
#define KZ (E_ + 2 * H_)   // 2560
#define NKB (KZ / 32)      // 80 K-blocks of 32

typedef short s8v  __attribute__((ext_vector_type(8)));
typedef float f32x4 __attribute__((ext_vector_type(4)));
typedef unsigned short us4 __attribute__((ext_vector_type(4)));
typedef unsigned short us8 __attribute__((ext_vector_type(8)));

// f32 -> bf16 round-to-nearest-even (bit trick, matches hardware RNE)
__device__ __forceinline__ unsigned short f2bf(float f)
{
    union { float f; unsigned u; } v; v.f = f;
    unsigned r = v.u + 0x7fffu + ((v.u >> 16) & 1u);
    return (unsigned short)(r >> 16);
}

// ---------------------------------------------------------------- fused prep:
// embed gather + the 4 bias broadcasts (dwdec, dwpos, gi, gh) in one launch
__global__ __launch_bounds__(256) void prep_kernel(
    const int* __restrict__ x, const float* __restrict__ emb, float* __restrict__ x_emb,
    const float* __restrict__ b_dec, float* __restrict__ dwdec,
    const float* __restrict__ b_pos, float* __restrict__ dwpos,
    const float* __restrict__ b_ih, float* __restrict__ gi,
    const float* __restrict__ b_hh, float* __restrict__ gh)
{
    int idx = blockIdx.x * 256 + threadIdx.x;
    if (idx < B_ * E_) { x_emb[idx] = emb[(size_t)x[idx >> 9] * E_ + (idx & 511)]; return; }
    idx -= B_ * E_;
    if (idx < B_ * H_) { dwdec[idx] = b_dec[idx & 1023]; return; }
    idx -= B_ * H_;
    if (idx < B_ * H_) { dwpos[idx] = b_pos[idx & 1023]; return; }
    idx -= B_ * H_;
    if (idx < B_ * 3 * H_) { gi[idx] = b_ih[idx % (3 * H_)]; return; }
    idx -= B_ * 3 * H_;
    gh[idx] = b_hh[idx % (3 * H_)];
}

// ---------------------------------------------------------------- generic f32 GEMM core (mid GEMMs)
// C[m,n] (+)= sum_k A[m,k] * W[n,k]    M=128 fixed, 256 threads, TILE_K=16
// CONCAT: A is the virtual concat [Aa (E_ cols) | Ab (H_ cols)]
template<int TILE_N, int MICRO_N, bool ATOMIC, bool CONCAT>
__device__ __forceinline__ void gemm_core(const float* __restrict__ A,
                                          const float* __restrict__ Aa,
                                          const float* __restrict__ Ab,
                                          const float* __restrict__ W,
                                          const float* __restrict__ bias,
                                          float* __restrict__ C,
                                          int N, int K, int kbeg, int kend,
                                          float (*As)[132], float (*Ws)[TILE_N + 4])
{
    constexpr int NT_N   = TILE_N / MICRO_N;   // threads along n
    constexpr int NT_M   = 256 / NT_N;         // threads along m
    constexpr int MICRO_M = 128 / NT_M;        // rows per thread
    const int tid = threadIdx.x;
    const int n0  = blockIdx.x * TILE_N;
    const int tn  = (tid % NT_N) * MICRO_N;
    const int tm  = (tid / NT_N) * MICRO_M;

    float acc[MICRO_M][MICRO_N] = {};

    for (int k0 = kbeg; k0 < kend; k0 += 16) {
        #pragma unroll
        for (int r = 0; r < 2; r++) {
            int v  = tid + 256 * r;
            int m  = v >> 2;
            int kk = (v & 3) << 2;
            int kcol = k0 + kk;
            float4 a4;
            if (CONCAT)
                a4 = (kcol < E_) ? *(const float4*)(Aa + (size_t)m * E_ + kcol)
                                 : *(const float4*)(Ab + (size_t)m * H_ + (kcol - E_));
            else
                a4 = *(const float4*)(A + (size_t)m * K + kcol);
            As[kk + 0][m] = a4.x; As[kk + 1][m] = a4.y;
            As[kk + 2][m] = a4.z; As[kk + 3][m] = a4.w;
        }
        for (int v = tid; v < TILE_N * 4; v += 256) {
            int n  = v >> 2;
            int kk = (v & 3) << 2;
            float4 w4 = *(const float4*)(W + (size_t)(n0 + n) * K + k0 + kk);
            Ws[kk + 0][n] = w4.x; Ws[kk + 1][n] = w4.y;
            Ws[kk + 2][n] = w4.z; Ws[kk + 3][n] = w4.w;
        }
        __syncthreads();
        #pragma unroll
        for (int kk = 0; kk < 16; kk++) {
            float a[MICRO_M], w[MICRO_N];
            #pragma unroll
            for (int i = 0; i < MICRO_M; i++) a[i] = As[kk][tm + i];
            #pragma unroll
            for (int j = 0; j < MICRO_N; j++) w[j] = Ws[kk][tn + j];
            #pragma unroll
            for (int i = 0; i < MICRO_M; i++)
                #pragma unroll
                for (int j = 0; j < MICRO_N; j++)
                    acc[i][j] = fmaf(a[i], w[j], acc[i][j]);
        }
        __syncthreads();
    }

    #pragma unroll
    for (int i = 0; i < MICRO_M; i++) {
        #pragma unroll
        for (int j = 0; j < MICRO_N; j++) {
            size_t off = (size_t)(tm + i) * N + n0 + tn + j;
            if (ATOMIC) atomicAdd(C + off, acc[i][j]);
            else        C[off] = acc[i][j] + bias[n0 + tn + j];
        }
    }
}

// dual mid GEMM: two problems selected by blockIdx.z, split-K via blockIdx.y,
// atomicAdd into bias-pre-initialized C. Problem 0 optionally reads A as concat.
template<bool CONCAT0>
__global__ __launch_bounds__(256) void gemm_dual(const float* A0, const float* A0a, const float* A0b,
                                                 const float* W0, float* C0, int K0, int kc0,
                                                 const float* A1, const float* W1, float* C1, int K1, int kc1,
                                                 int N)
{
    __shared__ float As[16][132];
    __shared__ float Ws[16][36];
    if (blockIdx.z == 0)
        gemm_core<32, 2, true, CONCAT0>(A0, A0a, A0b, W0, nullptr, C0, N, K0,
                                        blockIdx.y * kc0, blockIdx.y * kc0 + kc0, As, Ws);
    else
        gemm_core<32, 2, true, false>(A1, nullptr, nullptr, W1, nullptr, C1, N, K1,
                                      blockIdx.y * kc1, blockIdx.y * kc1 + kc1, As, Ws);
}

// ---------------------------------------------------------------- MFMA big GEMM (z)
// C[m,n] = sum_k A[m,k]*W[n,k] + bias[n].
// A2 is bf16 pre-arranged in MFMA fragment order by gru_concat:
//   A2[((kb*8 + mt)*64 + lane)*8 + j] = A[mt*16 + (lane&15)][kb*32 + (lane>>4)*8 + j]
// so each wave loads its A-fragments as contiguous 1 KB dwordx4 reads (L1/L2-hot,
// identical addresses across the 4 waves -> L1 broadcast). W (f32, HBM stream)
// is reg-staged + f2bf into a 4-deep LDS ring with a 2-ahead prefetch; barriers
// are raw s_barrier + lgkmcnt(0) only, so the W prefetch stays in flight across
// barriers (no vmcnt(0) drain).
__global__ __launch_bounds__(256) void gemm_z_mfma(const unsigned short* __restrict__ A2,
                                                   const float* __restrict__ W,
                                                   const float* __restrict__ bias,
                                                   float* __restrict__ C)
{
    __shared__ unsigned short Ws[4][64 * 40];   // 4 bufs x 64 rows x 32 bf16 (+8 pad)

    const int tid  = threadIdx.x;
    const int n0   = blockIdx.x * 64;
    const int w    = tid >> 6;
    const int lane = tid & 63;
    const int quad = lane >> 4;
    const int l16  = lane & 15;

    // W staging coords: 2 float4 per thread over the 64x32 f32 tile
    const int sn0 = tid >> 3;                 // rows 0..31 (r=0), +32 (r=1)
    const int sk  = (tid & 7) << 2;           // col 0,4,...,28
    const float* wp0 = W + (size_t)(n0 + sn0) * KZ + sk;
    const float* wp1 = W + (size_t)(n0 + sn0 + 32) * KZ + sk;
    const int wsoff0 = sn0 * 40 + sk;
    const int wsoff1 = (sn0 + 32) * 40 + sk;
    const unsigned short* ap = A2 + lane * 8;
    const int boff = (w * 16 + l16) * 40 + quad * 8;

    float4 wA[2], wB[2];
    f32x4 acc[8] = {};

    auto ldw = [&](int kb, float4 (&r)[2]) {
        r[0] = *(const float4*)(wp0 + kb * 32);
        r[1] = *(const float4*)(wp1 + kb * 32);
    };
    auto stw = [&](int buf, const float4 (&r)[2]) {
        us4 p0, p1;
        p0.x = f2bf(r[0].x); p0.y = f2bf(r[0].y); p0.z = f2bf(r[0].z); p0.w = f2bf(r[0].w);
        p1.x = f2bf(r[1].x); p1.y = f2bf(r[1].y); p1.z = f2bf(r[1].z); p1.w = f2bf(r[1].w);
        *(us4*)&Ws[buf][wsoff0] = p0;
        *(us4*)&Ws[buf][wsoff1] = p1;
    };
    // drain-free barrier: LDS visibility only; global loads stay in flight
    auto barrier = [&]() {
        asm volatile("s_waitcnt lgkmcnt(0)" ::: "memory");
        __builtin_amdgcn_s_barrier();
        asm volatile("" ::: "memory");
    };
    // one K-block: A-frag loads first (so their vmcnt waits don't retire the
    // younger W prefetch), then issue W(kb+2), MFMA, store W(kb+1) to LDS ring.
    auto subiter = [&](int kb, float4 (&wLd)[2], const float4 (&wSt)[2]) {
        s8v af[8];
        const unsigned short* ab = ap + (size_t)kb * 4096;
        #pragma unroll
        for (int mt = 0; mt < 8; mt++) af[mt] = *(const s8v*)(ab + mt * 512);
        if (kb + 2 < NKB) ldw(kb + 2, wLd);
        s8v bfrag = *(const s8v*)&Ws[kb & 3][boff];
        #pragma unroll
        for (int mt = 0; mt < 8; mt++)
            acc[mt] = __builtin_amdgcn_mfma_f32_16x16x32_bf16(af[mt], bfrag, acc[mt], 0, 0, 0);
        if (kb + 1 < NKB) stw((kb + 1) & 3, wSt);
        barrier();
    };

    // prologue: LDS[0] <- W(0); W(1) in flight in wB
    ldw(0, wA); ldw(1, wB);
    stw(0, wA);
    barrier();

    #pragma unroll 1
    for (int kb = 0; kb < NKB; kb += 2) {
        subiter(kb,     wA, wB);   // compute kb, prefetch kb+2 -> wA, store kb+1 (wB)
        subiter(kb + 1, wB, wA);   // compute kb+1, prefetch kb+3 -> wB, store kb+2 (wA)
    }

    const int n  = n0 + w * 16 + l16;
    const float bv = bias[n];
    #pragma unroll
    for (int mt = 0; mt < 8; mt++)
        #pragma unroll
        for (int r = 0; r < 4; r++)
            C[(size_t)(mt * 16 + quad * 4 + r) * V_ + n] = acc[mt][r] + bv;
}

// ---------------------------------------------------------------- pt = (len-1)*sigmoid(w_proj . tanh(dwpos))
__global__ __launch_bounds__(256) void pt_kernel(const int* __restrict__ masks,
                                                 const float* __restrict__ dwpos,
                                                 const float* __restrict__ w_proj,
                                                 float* __restrict__ pt)
{
    __shared__ int   smin_s[4];
    __shared__ float ssum[4];
    int b = blockIdx.x, tid = threadIdx.x;
    int lane = tid & 63, wv = tid >> 6;

    int first = (masks[tid * B_ + b] == 0) ? tid : S_;
    for (int off = 32; off; off >>= 1) first = min(first, __shfl_down(first, off, 64));
    if (lane == 0) smin_s[wv] = first;

    float sum = 0.f;
    for (int i = tid; i < H_; i += 256) sum += w_proj[i] * tanhf(dwpos[(size_t)b * H_ + i]);
    for (int off = 32; off; off >>= 1) sum += __shfl_down(sum, off, 64);
    if (lane == 0) ssum[wv] = sum;
    __syncthreads();
    if (tid == 0) {
        int   fz  = min(min(smin_s[0], smin_s[1]), min(smin_s[2], smin_s[3]));
        float tot = ssum[0] + ssum[1] + ssum[2] + ssum[3];
        float fht = 1.f / (1.f + expf(-tot));
        pt[b] = ((float)fz - 1.f) * fht;
    }
}

// ---------------------------------------------------------------- energy[s,b] = masked tanh(dw[b].enc[s,b])
__global__ __launch_bounds__(256) void energy_kernel(const float* __restrict__ dw,
                                                     const float* __restrict__ enc,
                                                     const int* __restrict__ masks,
                                                     float* __restrict__ energy)
{
    int wid  = (blockIdx.x << 2) + (threadIdx.x >> 6);  // wid = s*B + b
    int lane = threadIdx.x & 63;
    int b    = wid & (B_ - 1);
    const float4* ep = (const float4*)(enc + (size_t)wid * H_);
    const float4* dp = (const float4*)(dw + (size_t)b * H_);
    float acc = 0.f;
    #pragma unroll
    for (int i = 0; i < 4; i++) {
        float4 a = dp[lane + (i << 6)];
        float4 e = ep[lane + (i << 6)];
        acc += a.x * e.x + a.y * e.y + a.z * e.z + a.w * e.w;
    }
    for (int off = 32; off; off >>= 1) acc += __shfl_down(acc, off, 64);
    if (lane == 0)
        energy[wid] = masks[wid] ? tanhf(acc) : -1e30f;
}

// ---------------------------------------------------------------- softmax over S (per b) * local window
__global__ __launch_bounds__(256) void softmax_window(const float* __restrict__ energy,
                                                      const float* __restrict__ pt,
                                                      float* __restrict__ w_sb)
{
    __shared__ float sred[4];
    int b = blockIdx.x, s = threadIdx.x;
    int lane = s & 63, wv = s >> 6;
    float e = energy[s * B_ + b];

    float m = e;
    for (int off = 32; off; off >>= 1) m = fmaxf(m, __shfl_down(m, off, 64));
    if (lane == 0) sred[wv] = m;
    __syncthreads();
    m = fmaxf(fmaxf(sred[0], sred[1]), fmaxf(sred[2], sred[3]));
    __syncthreads();

    float ex = expf(e - m);
    float l = ex;
    for (int off = 32; off; off >>= 1) l += __shfl_down(l, off, 64);
    if (lane == 0) sred[wv] = l;
    __syncthreads();
    l = sred[0] + sred[1] + sred[2] + sred[3];

    float aw   = ex / l;
    float ptb  = pt[b];
    float fs   = (float)s;
    float pmax = floorf(ptb + 5.f);
    float pmin = floorf(fmaxf(ptb - 5.f, 0.f));
    float d    = ptb - fs;
    float win  = ((fs < pmax) && (fs >= pmin)) ? expf(-(d * d) * (1.f / 12.5f)) : 0.f;
    w_sb[s * B_ + b] = aw * win;
}

// ---------------------------------------------------------------- context[b,h] = sum_s w[s,b]*enc[s,b,h] (sparse window)
__global__ __launch_bounds__(256) void context_kernel(const float* __restrict__ w_sb,
                                                      const float* __restrict__ enc,
                                                      const float* __restrict__ pt,
                                                      float* __restrict__ ctx)
{
    int b = blockIdx.y;
    int h = blockIdx.x * 256 + threadIdx.x;
    float ptb = pt[b];
    int smin = (int)floorf(fmaxf(ptb - 5.f, 0.f));
    int smax = min((int)floorf(ptb + 5.f), S_);
    float acc = 0.f;
    for (int s = smin; s < smax; s++)
        acc += w_sb[s * B_ + b] * enc[(size_t)(s * B_ + b) * H_ + h];
    ctx[(size_t)b * H_ + h] = acc;
}

// ---------------------------------------------------------------- fused GRU epilogue + A2 writer
// Thread gid <-> (kb, mt, l): emits A2 in gemm_z fragment order with perfectly
// coalesced us8 stores; the GRU range also writes out_h.
__global__ __launch_bounds__(256) void gru_concat(const float* __restrict__ x_emb,
                                                  const float* __restrict__ gi,
                                                  const float* __restrict__ gh,
                                                  const float* __restrict__ phd,
                                                  const float* __restrict__ ctx,
                                                  float* __restrict__ out_h,
                                                  unsigned short* __restrict__ A2)
{
    int gid = blockIdx.x * 256 + threadIdx.x;   // 80*8*64 = 40960
    int l   = gid & 63;
    int mt  = (gid >> 6) & 7;
    int kb  = gid >> 9;
    int b   = mt * 16 + (l & 15);
    int k0  = kb * 32 + ((l >> 4) << 3);        // 8 consecutive k, same region

    float v[8];
    if (k0 < E_) {
        const float* p = x_emb + (size_t)b * E_ + k0;
        #pragma unroll
        for (int j = 0; j < 8; j++) v[j] = p[j];
    } else if (k0 < E_ + H_) {
        int i0 = k0 - E_;
        const float* gib = gi + (size_t)b * 3 * H_ + i0;
        const float* ghb = gh + (size_t)b * 3 * H_ + i0;
        const float* ph  = phd + (size_t)b * H_ + i0;
        float* oh = out_h + (size_t)b * H_ + i0;
        #pragma unroll
        for (int j = 0; j < 8; j++) {
            float ir = gib[j], iz = gib[H_ + j], in_ = gib[2 * H_ + j];
            float hr = ghb[j], hz = ghb[H_ + j], hn  = ghb[2 * H_ + j];
            float r  = 1.f / (1.f + expf(-(ir + hr)));
            float zg = 1.f / (1.f + expf(-(iz + hz)));
            float n  = tanhf(in_ + r * hn);
            float h  = (1.f - zg) * n + zg * ph[j];
            oh[j] = h;
            v[j] = h;
        }
    } else {
        const float* p = ctx + (size_t)b * H_ + (k0 - E_ - H_);
        #pragma unroll
        for (int j = 0; j < 8; j++) v[j] = p[j];
    }
    us8 o;
    #pragma unroll
    for (int j = 0; j < 8; j++) o[j] = f2bf(v[j]);
    *(us8*)(A2 + (size_t)gid * 8) = o;
}

// ---------------------------------------------------------------- launch
extern "C" void kernel_launch(void* const* d_in, const int* in_sizes, int n_in,
                              void* d_out, int out_size, void* d_ws, size_t ws_size,
                              hipStream_t stream)
{
    const int*   x      = (const int*)  d_in[0];
    const float* phd    = (const float*)d_in[1];   // (1,B,H)
    const float* enc    = (const float*)d_in[2];   // (S,B,H)
    const int*   masks  = (const int*)  d_in[3];   // (S,B)
    const float* emb    = (const float*)d_in[4];
    const float* W_dec  = (const float*)d_in[5];
    const float* b_dec  = (const float*)d_in[6];
    const float* W_pos  = (const float*)d_in[7];
    const float* b_pos  = (const float*)d_in[8];
    const float* w_proj = (const float*)d_in[9];
    const float* W_ih   = (const float*)d_in[10];
    const float* b_ih   = (const float*)d_in[11];
    const float* W_hh   = (const float*)d_in[12];
    const float* b_hh   = (const float*)d_in[13];
    const float* W_fc   = (const float*)d_in[14];
    const float* b_fc   = (const float*)d_in[15];

    float* out_z = (float*)d_out;                   // (1,B,V)
    float* out_h = out_z + (size_t)B_ * V_;         // (1,B,H)

    float* ws       = (float*)d_ws;
    float* x_emb    = ws;  ws += B_ * E_;
    float* dwdec    = ws;  ws += B_ * H_;
    float* dwpos    = ws;  ws += B_ * H_;
    float* pt       = ws;  ws += 128;
    float* energy   = ws;  ws += S_ * B_;
    float* w_sb     = ws;  ws += S_ * B_;
    float* ctx      = ws;  ws += B_ * H_;
    float* gi       = ws;  ws += B_ * 3 * H_;
    float* gh       = ws;  ws += B_ * 3 * H_;
    unsigned short* A2 = (unsigned short*)ws;       // B*(E+2H) bf16, fragment order

    // embed + 4 bias inits fused: (65536 + 2*131072 + 2*393216) / 256 = 4352 blocks
    prep_kernel<<<4352, 256, 0, stream>>>(x, emb, x_emb, b_dec, dwdec, b_pos, dwpos,
                                          b_ih, gi, b_hh, gh);

    gemm_dual<false><<<dim3(H_ / 32, 4, 2), 256, 0, stream>>>(
        phd, nullptr, nullptr, W_dec, dwdec, H_, 256,
        phd,                   W_pos, dwpos, H_, 256, H_);

    pt_kernel<<<B_, 256, 0, stream>>>(masks, dwpos, w_proj, pt);
    energy_kernel<<<S_ * B_ / 4, 256, 0, stream>>>(dwdec, enc, masks, energy);
    softmax_window<<<B_, 256, 0, stream>>>(energy, pt, w_sb);
    context_kernel<<<dim3(H_ / 256, B_), 256, 0, stream>>>(w_sb, enc, pt, ctx);

    // gi/gh GEMMs; problem 0 reads A as virtual concat [x_emb | ctx] (no copy kernel)
    gemm_dual<true><<<dim3(3 * H_ / 32, 4, 2), 256, 0, stream>>>(
        nullptr, x_emb, ctx, W_ih, gi, E_ + H_, 384,
        phd,                 W_hh, gh, H_,      256, 3 * H_);

    // GRU + new_input concat fused; emits A2 in MFMA fragment order
    gru_concat<<<B_ * KZ / 8 / 256, 256, 0, stream>>>(x_emb, gi, gh, phd, ctx, out_h, A2);

    // z = new_input @ W_fc.T + b_fc  (bf16 MFMA, 500 blocks, pipelined W stream)
    gemm_z_mfma<<<V_ / 64, 256, 0, stream>>>(A2, W_fc, b_fc, out_z);
}